// Round 1
// baseline (576.630 us; speedup 1.0000x reference)
//
#include <hip/hip_runtime.h>
#include <hip/hip_bf16.h>

// Problem constants
#define N_TOKENS 8192
#define D_IN     2048
#define HIDDEN   2048
#define N_EXP    8
#define CAP      N_TOKENS       // worst-case tokens per expert (top-2)
#define GATE_BLOCKS 256         // 32 tokens per block
#define TPOSE_BLOCKS (N_EXP * 32 * 32)  // 8192 (64x64 tiles)

typedef __bf16 bf16x8 __attribute__((ext_vector_type(8)));
typedef float  f32x4  __attribute__((ext_vector_type(4)));

// Workspace layout (bytes):
//   [0, 1024)              cnt[8*32]  (one counter per 128B line; zeroed per launch)
//   [4096, +8*CAP*4)       bucket_tok
//   [266240, +8*CAP*4)     bucket_w
//   [1<<20, +N*D*2)        x_bf16
//   [34603008, +E*D*H*2)   We_t  (bf16, [e][h][d])
#define OFF_CNT   0
#define OFF_TOK   4096
#define OFF_W     266240
#define OFF_XBF   1048576
#define OFF_WET   34603008

__device__ __forceinline__ unsigned short f2bf(float f) {
  unsigned int u = __builtin_bit_cast(unsigned int, f);
  u += 0x7fffu + ((u >> 16) & 1u);   // RNE
  return (unsigned short)(u >> 16);
}

__device__ __forceinline__ void g2l16(const void* g, void* l) {
  // async global->LDS, 16B/lane; LDS dest is wave-uniform base + lane*16
  __builtin_amdgcn_global_load_lds(
      (__attribute__((address_space(1))) void*)g,
      (__attribute__((address_space(3))) void*)l, 16, 0, 0);
}

// ---------------------------------------------------------------------------
// Fused prep kernel:
//   blocks [0, GATE_BLOCKS)                : gating + x fp32->bf16 conversion
//   blocks [GATE_BLOCKS, +TPOSE_BLOCKS)    : We [e][d][h] f32 -> We_t [e][h][d] bf16
// ---------------------------------------------------------------------------
union PrepSM {
  float tile[64][68];      // transpose path (17.4 KB)
  struct {
    int   lcnt[8];
    int   base[8];
    int   ltok[8][32];     // per-block, per-expert token lists (<=32 tokens/block)
    float lw[8][32];
  } g;
};

__global__ __launch_bounds__(256) void prep_kernel(
    const float* __restrict__ x, const float* __restrict__ Wg,
    const float* __restrict__ bg, const float* __restrict__ We,
    unsigned short* __restrict__ xbf, unsigned short* __restrict__ wet,
    int* __restrict__ cnt, int* __restrict__ btok, float* __restrict__ bw)
{
  __shared__ PrepSM sm;
  const int tid = threadIdx.x;

  if (blockIdx.x >= GATE_BLOCKS) {
    // ---------------- transpose + bf16 convert ----------------
    const int id = blockIdx.x - GATE_BLOCKS;
    const int e  = id >> 10;
    const int rem = id & 1023;
    const int d0 = (rem >> 5) << 6;
    const int h0 = (rem & 31) << 6;
    const int r  = tid >> 2;     // 0..63
    const int g  = tid & 3;      // 0..3

    const float* src = We + ((size_t)e * D_IN + d0 + r) * HIDDEN + h0 + g * 16;
#pragma unroll
    for (int i = 0; i < 4; ++i)
      *(float4*)&sm.tile[r][g * 16 + i * 4] = *(const float4*)(src + i * 4);
    __syncthreads();

    union { unsigned short s[16]; uint4 q[2]; } u;
#pragma unroll
    for (int i = 0; i < 16; ++i) u.s[i] = f2bf(sm.tile[g * 16 + i][r]);
    uint4* dst = (uint4*)(wet + ((size_t)e * HIDDEN + h0 + r) * D_IN + d0 + g * 16);
    dst[0] = u.q[0];
    dst[1] = u.q[1];
    return;
  }

  // ---------------- gating (32 tokens/block, 8/wave) ----------------
  const int lane = tid & 63;
  const int wid  = tid >> 6;
  if (tid < 8) sm.g.lcnt[tid] = 0;
  __syncthreads();

  const int tb = blockIdx.x * 32 + wid * 8;
  for (int tk = 0; tk < 8; ++tk) {
    const int n = tb + tk;
    const float* xr = x + (size_t)n * D_IN;
    unsigned short* xbr = xbf + (size_t)n * D_IN;

    // fused x -> bf16 (vectorized, coalesced)
#pragma unroll
    for (int c = 0; c < 8; ++c) {
      const int d = c * 256 + lane * 4;
      float4 xv = *(const float4*)(xr + d);
      uint2 pk;
      pk.x = (unsigned int)f2bf(xv.x) | ((unsigned int)f2bf(xv.y) << 16);
      pk.y = (unsigned int)f2bf(xv.z) | ((unsigned int)f2bf(xv.w) << 16);
      *(uint2*)(xbr + d) = pk;
    }

    // logits: 1 d per lane -> Wg row load is 32B/lane at 32B stride (16 lines/instr)
    float acc[8];
#pragma unroll
    for (int e = 0; e < 8; ++e) acc[e] = 0.f;
#pragma unroll 4
    for (int c = 0; c < 32; ++c) {
      const int d = c * 64 + lane;
      const float xv = xr[d];
      const float4 g0 = *(const float4*)(Wg + (size_t)d * 8);
      const float4 g1 = *(const float4*)(Wg + (size_t)d * 8 + 4);
      acc[0] += xv * g0.x; acc[1] += xv * g0.y;
      acc[2] += xv * g0.z; acc[3] += xv * g0.w;
      acc[4] += xv * g1.x; acc[5] += xv * g1.y;
      acc[6] += xv * g1.z; acc[7] += xv * g1.w;
    }
#pragma unroll
    for (int e = 0; e < 8; ++e) {
      float v = acc[e];
      v += __shfl_down(v, 32); v += __shfl_down(v, 16); v += __shfl_down(v, 8);
      v += __shfl_down(v, 4);  v += __shfl_down(v, 2);  v += __shfl_down(v, 1);
      acc[e] = v;
    }

    if (lane == 0) {
      float lg[8], p[8];
      float mx = -1e30f;
#pragma unroll
      for (int e = 0; e < 8; ++e) { lg[e] = acc[e] + bg[e]; mx = fmaxf(mx, lg[e]); }
      float s = 0.f;
#pragma unroll
      for (int e = 0; e < 8; ++e) { p[e] = expf(lg[e] - mx); s += p[e]; }
      const float inv = 1.f / s;
      int e1 = 0;
#pragma unroll
      for (int e = 1; e < 8; ++e) if (lg[e] > lg[e1]) e1 = e;
      int e2 = (e1 == 0) ? 1 : 0;
#pragma unroll
      for (int e = 0; e < 8; ++e) if (e != e1 && lg[e] > lg[e2]) e2 = e;

      const int s1 = atomicAdd(&sm.g.lcnt[e1], 1);
      sm.g.ltok[e1][s1] = n;  sm.g.lw[e1][s1] = p[e1] * inv;
      const int s2 = atomicAdd(&sm.g.lcnt[e2], 1);
      sm.g.ltok[e2][s2] = n;  sm.g.lw[e2][s2] = p[e2] * inv;
    }
  }
  __syncthreads();

  // one global atomic per expert per block (counters on separate 128B lines)
  if (tid < 8) sm.g.base[tid] = atomicAdd(&cnt[tid * 32], sm.g.lcnt[tid]);
  __syncthreads();

  const int e = tid >> 5, i = tid & 31;
  if (i < sm.g.lcnt[e]) {
    const int o = e * CAP + sm.g.base[e] + i;
    btok[o] = sm.g.ltok[e][i];
    bw[o]   = sm.g.lw[e][i];
  }
}

// ---------------------------------------------------------------------------
// Grouped GEMM over expert buckets (128x128 tile, BK=64, bf16 MFMA)
// grid = (h_tiles=16, m_tiles=64, experts=8), 256 threads (4 waves, 2x2)
//
// Pipelined K-loop (T3/T4 mechanism, K-tile granular):
//   - double-buffered LDS (2 x 32 KB = 64 KB -> 2 blocks/CU)
//   - loads issued 2 K-tiles ahead; never drained to vmcnt(0) in the loop
//   - per iter: vmcnt(8) [own 8 loads of tile t landed; tile t+1's in flight]
//     -> barrier -> ds_read all 16 frags to regs -> lgkmcnt(0) -> barrier
//     -> re-stage tile t+2 into the freed buffer -> setprio(1) 32xMFMA setprio(0)
// LDS tiles XOR-swizzled (kc ^= row&7) to kill 16-way bank conflicts.
// ---------------------------------------------------------------------------
__global__ __launch_bounds__(256, 2) void moe_gemm(
    const unsigned short* __restrict__ xbf, const unsigned short* __restrict__ wet,
    const float* __restrict__ be, const int* __restrict__ cnt,
    const int* __restrict__ btok, const float* __restrict__ bw,
    float* __restrict__ out)
{
  const int e  = blockIdx.z;
  const int M  = cnt[e * 32];
  const int m0 = blockIdx.y * 128;
  if (m0 >= M) return;
  const int h0 = blockIdx.x * 128;

  __shared__ __align__(16) unsigned short As[2][128 * 64];
  __shared__ __align__(16) unsigned short Bs[2][128 * 64];

  const int tid  = threadIdx.x;
  const int wid  = tid >> 6;
  const int lane = tid & 63;
  const int wm   = wid >> 1;   // 0..1
  const int wn   = wid & 1;    // 0..1

  const int* etok = btok + e * CAP;
  const float* ew = bw + e * CAP;

  // swizzled per-lane source column: data for k-chunk (c ^ localrow) goes at lane pos c
  const int kcs = (((lane & 7) ^ (lane >> 3)) * 8);

  size_t asrc[4], bsrc[4];
#pragma unroll
  for (int j = 0; j < 4; ++j) {
    const int c = wid * 4 + j;               // chunk 0..15 (8 rows each)
    const int r = c * 8 + (lane >> 3);       // row within 128-tile
    int ar = m0 + r;
    if (ar >= M) ar = m0;                    // clamp (discarded in epilogue)
    const int tok = etok[ar];
    asrc[j] = (size_t)tok * D_IN + kcs;
    bsrc[j] = ((size_t)e * HIDDEN + h0 + r) * D_IN + kcs;
  }

  f32x4 acc[4][4];
#pragma unroll
  for (int i = 0; i < 4; ++i)
#pragma unroll
    for (int j = 0; j < 4; ++j) acc[i][j] = (f32x4){0.f, 0.f, 0.f, 0.f};

  // ---- prologue: stage K-tile 0 into buf0, K-tile 1 into buf1 ----
  // fence between the two groups so vmcnt FIFO order is exactly tile0 then tile1
#pragma unroll
  for (int j = 0; j < 4; ++j)
    g2l16(xbf + asrc[j], &As[0][(wid * 4 + j) * 512]);
#pragma unroll
  for (int j = 0; j < 4; ++j)
    g2l16(wet + bsrc[j], &Bs[0][(wid * 4 + j) * 512]);
  asm volatile("" ::: "memory");
#pragma unroll
  for (int j = 0; j < 4; ++j)
    g2l16(xbf + asrc[j] + 64, &As[1][(wid * 4 + j) * 512]);
#pragma unroll
  for (int j = 0; j < 4; ++j)
    g2l16(wet + bsrc[j] + 64, &Bs[1][(wid * 4 + j) * 512]);

  // ---- main loop: T = D_IN/64 = 32 K-tiles ----
#pragma unroll 1
  for (int t = 0; t < D_IN / 64; ++t) {
    const int cur = t & 1;
    const unsigned short* Ab = &As[cur][0];
    const unsigned short* Bb = &Bs[cur][0];

    // tile t's 8 staging loads landed (tile t+1's 8 may remain in flight)
    asm volatile("s_waitcnt vmcnt(8)" ::: "memory");
    __builtin_amdgcn_s_barrier();
    __builtin_amdgcn_sched_barrier(0);

    // read the full fragment set for this K-tile into registers
    bf16x8 af[4][2], bfr[4][2];
#pragma unroll
    for (int kh = 0; kh < 2; ++kh) {
#pragma unroll
      for (int fm = 0; fm < 4; ++fm) {
        const int row = wm * 64 + fm * 16 + (lane & 15);
        const int kc  = kh * 4 + (lane >> 4);
        af[fm][kh] = __builtin_bit_cast(bf16x8,
            *(const uint4*)(Ab + row * 64 + ((kc ^ (row & 7)) * 8)));
      }
#pragma unroll
      for (int fn = 0; fn < 4; ++fn) {
        const int row = wn * 64 + fn * 16 + (lane & 15);
        const int kc  = kh * 4 + (lane >> 4);
        bfr[fn][kh] = __builtin_bit_cast(bf16x8,
            *(const uint4*)(Bb + row * 64 + ((kc ^ (row & 7)) * 8)));
      }
    }

    // all LDS reads complete -> buffer free for restaging after the barrier
    asm volatile("s_waitcnt lgkmcnt(0)" ::: "memory");
    __builtin_amdgcn_sched_barrier(0);
    __builtin_amdgcn_s_barrier();
    __builtin_amdgcn_sched_barrier(0);

    // stage K-tile t+2 into the buffer we just finished reading
    // (tail iters re-stage k=0: valid addresses, never consumed)
    int kp = (t + 2) * 64;
    if (kp >= D_IN) kp = 0;
#pragma unroll
    for (int j = 0; j < 4; ++j)
      g2l16(xbf + asrc[j] + kp, &As[cur][(wid * 4 + j) * 512]);
#pragma unroll
    for (int j = 0; j < 4; ++j)
      g2l16(wet + bsrc[j] + kp, &Bs[cur][(wid * 4 + j) * 512]);
    __builtin_amdgcn_sched_barrier(0);

    // pure-MFMA phase
    __builtin_amdgcn_s_setprio(1);
#pragma unroll
    for (int kh = 0; kh < 2; ++kh)
#pragma unroll
      for (int fm = 0; fm < 4; ++fm)
#pragma unroll
        for (int fn = 0; fn < 4; ++fn)
          acc[fm][fn] = __builtin_amdgcn_mfma_f32_16x16x32_bf16(
              af[fm][kh], bfr[fn][kh], acc[fm][fn], 0, 0, 0);
    __builtin_amdgcn_s_setprio(0);
  }

  // Epilogue: out[tok][h] += w * (acc + be[e][h]); C layout: col=lane&15, row=(lane>>4)*4+reg
  float bias[4];
#pragma unroll
  for (int fn = 0; fn < 4; ++fn)
    bias[fn] = be[e * HIDDEN + h0 + wn * 64 + fn * 16 + (lane & 15)];

#pragma unroll
  for (int fm = 0; fm < 4; ++fm) {
    const int rbase = m0 + wm * 64 + fm * 16 + (lane >> 4) * 4;
#pragma unroll
    for (int reg = 0; reg < 4; ++reg) {
      const int r = rbase + reg;
      if (r < M) {
        const int tok = etok[r];
        const float w = ew[r];
        float* orow = out + (size_t)tok * HIDDEN + h0 + wn * 64 + (lane & 15);
#pragma unroll
        for (int fn = 0; fn < 4; ++fn)
          atomicAdd(orow + fn * 16, w * (acc[fm][fn][reg] + bias[fn]));
      }
    }
  }
}

// ---------------------------------------------------------------------------
extern "C" void kernel_launch(void* const* d_in, const int* in_sizes, int n_in,
                              void* d_out, int out_size, void* d_ws, size_t ws_size,
                              hipStream_t stream) {
  const float* x  = (const float*)d_in[0];
  const float* Wg = (const float*)d_in[1];
  const float* bg = (const float*)d_in[2];
  const float* We = (const float*)d_in[3];
  const float* be = (const float*)d_in[4];
  float* out = (float*)d_out;

  char* ws = (char*)d_ws;
  int*            cnt  = (int*)(ws + OFF_CNT);
  int*            btok = (int*)(ws + OFF_TOK);
  float*          bw   = (float*)(ws + OFF_W);
  unsigned short* xbf  = (unsigned short*)(ws + OFF_XBF);
  unsigned short* wet  = (unsigned short*)(ws + OFF_WET);

  hipMemsetAsync(d_out, 0, (size_t)out_size * sizeof(float), stream);
  hipMemsetAsync(cnt, 0, 8 * 32 * sizeof(int), stream);

  prep_kernel<<<GATE_BLOCKS + TPOSE_BLOCKS, 256, 0, stream>>>(
      x, Wg, bg, We, xbf, wet, cnt, btok, bw);
  moe_gemm<<<dim3(HIDDEN / 128, N_TOKENS / 128, N_EXP), 256, 0, stream>>>(
      xbf, wet, be, cnt, btok, bw, out);
}

// Round 2
// 569.376 us; speedup vs baseline: 1.0127x; 1.0127x over previous
//
#include <hip/hip_runtime.h>
#include <hip/hip_bf16.h>

// Problem constants
#define N_TOKENS 8192
#define D_IN     2048
#define HIDDEN   2048
#define N_EXP    8
#define CAP      N_TOKENS       // worst-case tokens per expert (top-2)
#define GATE_BLOCKS 256         // 32 tokens per block
#define TPOSE_BLOCKS (N_EXP * 32 * 32)  // 8192 (64x64 tiles)

typedef __bf16 bf16x8 __attribute__((ext_vector_type(8)));
typedef float  f32x4  __attribute__((ext_vector_type(4)));

// Workspace layout (bytes):
//   [0, 1024)              cnt[8*32]  (one counter per 128B line; zeroed per launch)
//   [4096, +8*CAP*4)       bucket_tok
//   [266240, +8*CAP*4)     bucket_w
//   [1<<20, +N*D*2)        x_bf16
//   [34603008, +E*D*H*2)   We_t  (bf16, [e][h][d])
#define OFF_CNT   0
#define OFF_TOK   4096
#define OFF_W     266240
#define OFF_XBF   1048576
#define OFF_WET   34603008

__device__ __forceinline__ unsigned short f2bf(float f) {
  unsigned int u = __builtin_bit_cast(unsigned int, f);
  u += 0x7fffu + ((u >> 16) & 1u);   // RNE
  return (unsigned short)(u >> 16);
}

__device__ __forceinline__ void g2l16(const void* g, void* l) {
  // async global->LDS, 16B/lane; LDS dest is wave-uniform base + lane*16
  __builtin_amdgcn_global_load_lds(
      (__attribute__((address_space(1))) void*)g,
      (__attribute__((address_space(3))) void*)l, 16, 0, 0);
}

// ---------------------------------------------------------------------------
// Fused prep kernel (unchanged from the 210us-GEMM baseline):
//   blocks [0, GATE_BLOCKS)                : gating + x fp32->bf16 conversion
//   blocks [GATE_BLOCKS, +TPOSE_BLOCKS)    : We [e][d][h] f32 -> We_t [e][h][d] bf16
// ---------------------------------------------------------------------------
union PrepSM {
  float tile[64][68];      // transpose path (17.4 KB)
  struct {
    int   lcnt[8];
    int   base[8];
    int   ltok[8][32];     // per-block, per-expert token lists (<=32 tokens/block)
    float lw[8][32];
  } g;
};

__global__ __launch_bounds__(256) void prep_kernel(
    const float* __restrict__ x, const float* __restrict__ Wg,
    const float* __restrict__ bg, const float* __restrict__ We,
    unsigned short* __restrict__ xbf, unsigned short* __restrict__ wet,
    int* __restrict__ cnt, int* __restrict__ btok, float* __restrict__ bw)
{
  __shared__ PrepSM sm;
  const int tid = threadIdx.x;

  if (blockIdx.x >= GATE_BLOCKS) {
    // ---------------- transpose + bf16 convert ----------------
    const int id = blockIdx.x - GATE_BLOCKS;
    const int e  = id >> 10;
    const int rem = id & 1023;
    const int d0 = (rem >> 5) << 6;
    const int h0 = (rem & 31) << 6;
    const int r  = tid >> 2;     // 0..63
    const int g  = tid & 3;      // 0..3

    const float* src = We + ((size_t)e * D_IN + d0 + r) * HIDDEN + h0 + g * 16;
#pragma unroll
    for (int i = 0; i < 4; ++i)
      *(float4*)&sm.tile[r][g * 16 + i * 4] = *(const float4*)(src + i * 4);
    __syncthreads();

    union { unsigned short s[16]; uint4 q[2]; } u;
#pragma unroll
    for (int i = 0; i < 16; ++i) u.s[i] = f2bf(sm.tile[g * 16 + i][r]);
    uint4* dst = (uint4*)(wet + ((size_t)e * HIDDEN + h0 + r) * D_IN + d0 + g * 16);
    dst[0] = u.q[0];
    dst[1] = u.q[1];
    return;
  }

  // ---------------- gating (32 tokens/block, 8/wave) ----------------
  const int lane = tid & 63;
  const int wid  = tid >> 6;
  if (tid < 8) sm.g.lcnt[tid] = 0;
  __syncthreads();

  const int tb = blockIdx.x * 32 + wid * 8;
  for (int tk = 0; tk < 8; ++tk) {
    const int n = tb + tk;
    const float* xr = x + (size_t)n * D_IN;
    unsigned short* xbr = xbf + (size_t)n * D_IN;

    // fused x -> bf16 (vectorized, coalesced)
#pragma unroll
    for (int c = 0; c < 8; ++c) {
      const int d = c * 256 + lane * 4;
      float4 xv = *(const float4*)(xr + d);
      uint2 pk;
      pk.x = (unsigned int)f2bf(xv.x) | ((unsigned int)f2bf(xv.y) << 16);
      pk.y = (unsigned int)f2bf(xv.z) | ((unsigned int)f2bf(xv.w) << 16);
      *(uint2*)(xbr + d) = pk;
    }

    // logits: 1 d per lane -> Wg row load is 32B/lane at 32B stride
    float acc[8];
#pragma unroll
    for (int e = 0; e < 8; ++e) acc[e] = 0.f;
#pragma unroll 4
    for (int c = 0; c < 32; ++c) {
      const int d = c * 64 + lane;
      const float xv = xr[d];
      const float4 g0 = *(const float4*)(Wg + (size_t)d * 8);
      const float4 g1 = *(const float4*)(Wg + (size_t)d * 8 + 4);
      acc[0] += xv * g0.x; acc[1] += xv * g0.y;
      acc[2] += xv * g0.z; acc[3] += xv * g0.w;
      acc[4] += xv * g1.x; acc[5] += xv * g1.y;
      acc[6] += xv * g1.z; acc[7] += xv * g1.w;
    }
#pragma unroll
    for (int e = 0; e < 8; ++e) {
      float v = acc[e];
      v += __shfl_down(v, 32); v += __shfl_down(v, 16); v += __shfl_down(v, 8);
      v += __shfl_down(v, 4);  v += __shfl_down(v, 2);  v += __shfl_down(v, 1);
      acc[e] = v;
    }

    if (lane == 0) {
      float lg[8], p[8];
      float mx = -1e30f;
#pragma unroll
      for (int e = 0; e < 8; ++e) { lg[e] = acc[e] + bg[e]; mx = fmaxf(mx, lg[e]); }
      float s = 0.f;
#pragma unroll
      for (int e = 0; e < 8; ++e) { p[e] = expf(lg[e] - mx); s += p[e]; }
      const float inv = 1.f / s;
      int e1 = 0;
#pragma unroll
      for (int e = 1; e < 8; ++e) if (lg[e] > lg[e1]) e1 = e;
      int e2 = (e1 == 0) ? 1 : 0;
#pragma unroll
      for (int e = 0; e < 8; ++e) if (e != e1 && lg[e] > lg[e2]) e2 = e;

      const int s1 = atomicAdd(&sm.g.lcnt[e1], 1);
      sm.g.ltok[e1][s1] = n;  sm.g.lw[e1][s1] = p[e1] * inv;
      const int s2 = atomicAdd(&sm.g.lcnt[e2], 1);
      sm.g.ltok[e2][s2] = n;  sm.g.lw[e2][s2] = p[e2] * inv;
    }
  }
  __syncthreads();

  if (tid < 8) sm.g.base[tid] = atomicAdd(&cnt[tid * 32], sm.g.lcnt[tid]);
  __syncthreads();

  const int e = tid >> 5, i = tid & 31;
  if (i < sm.g.lcnt[e]) {
    const int o = e * CAP + sm.g.base[e] + i;
    btok[o] = sm.g.ltok[e][i];
    bw[o]   = sm.g.lw[e][i];
  }
}

// ---------------------------------------------------------------------------
// Grouped GEMM, 8-phase 256^2 schedule (m201/m248 structure ported to buckets)
// grid = (h_tiles=8, m_tiles=32, experts=8), 512 threads (8 waves, 2Mx4N)
//
// LDS: per dbuf (K-tile parity), per matrix, two k-halves [256 rows][32 k] bf16
//      = 2*2*2*16KB = 128KB -> 1 block/CU.
// Phase = quadrant (k-step ks, n-half nh): {ds_read 10|2 x b128; stage 1
//      half (2 g2l16); [vmcnt(8) even phases]; barrier; lgkmcnt(0); 16 MFMA}.
// Stage->read distance = 6 phases; read->restage distance >= 1 barrier+lgkm.
// vmcnt never drained to 0 in the loop (T4). setprio around MFMA (T5).
// Swizzle: slot = kq ^ ((row>>1)&3) on 4x16B slots/row; inverse applied on the
// per-lane GLOBAL source (rule 21), LDS dest stays linear for global_load_lds.
// ---------------------------------------------------------------------------
__global__ __launch_bounds__(512, 2) void moe_gemm(
    const unsigned short* __restrict__ xbf, const unsigned short* __restrict__ wet,
    const float* __restrict__ be, const int* __restrict__ cnt,
    const int* __restrict__ btok, const float* __restrict__ bw,
    float* __restrict__ out)
{
  const int e  = blockIdx.z;
  const int M  = cnt[e * 32];
  const int m0 = blockIdx.y * 256;
  if (m0 >= M) return;
  const int h0 = blockIdx.x * 256;

  __shared__ __align__(16) unsigned short As[2][2][256 * 32];  // [dbuf][ks]
  __shared__ __align__(16) unsigned short Bs[2][2][256 * 32];

  const int tid  = threadIdx.x;
  const int wid  = tid >> 6;       // 0..7
  const int lane = tid & 63;
  const int wm   = wid >> 2;       // 0..1  (128 rows each)
  const int wn   = wid & 3;        // 0..3  (64 cols each)

  const int* etok = btok + e * CAP;
  const float* ew = bw + e * CAP;

  // staging: chunk c = wid*2+j covers rows c*16..c*16+15 of a half.
  // lane -> row c*16 + (lane>>2), slot (lane&3). Source k-chunk is
  // pre-swizzled: kq = (lane&3) ^ ((row>>1)&3), and (row>>1)&3 == (lane>>3)&3.
  const int kqs = (((lane & 3) ^ ((lane >> 3) & 3)) * 8);

  size_t asrc[2], bsrc[2];
#pragma unroll
  for (int j = 0; j < 2; ++j) {
    const int r = (wid * 2 + j) * 16 + (lane >> 2);
    int ar = m0 + r;
    if (ar >= M) ar = m0;                    // clamp (discarded in epilogue)
    asrc[j] = (size_t)etok[ar] * D_IN + kqs;
    bsrc[j] = ((size_t)e * HIDDEN + h0 + r) * D_IN + kqs;
  }

  f32x4 acc[8][4];
#pragma unroll
  for (int i = 0; i < 8; ++i)
#pragma unroll
    for (int j = 0; j < 4; ++j) acc[i][j] = (f32x4){0.f, 0.f, 0.f, 0.f};

  bf16x8 af[8], bfr[4];

#define SG_A(db_, ks_, ko_) {                                                  \
    const int ko = ((ko_) < D_IN) ? (ko_) : 0;                                 \
    g2l16(xbf + asrc[0] + ko, &As[db_][ks_][(wid * 2 + 0) * 512]);             \
    g2l16(xbf + asrc[1] + ko, &As[db_][ks_][(wid * 2 + 1) * 512]);             \
    asm volatile("" ::: "memory"); }
#define SG_B(db_, ks_, ko_) {                                                  \
    const int ko = ((ko_) < D_IN) ? (ko_) : 0;                                 \
    g2l16(wet + bsrc[0] + ko, &Bs[db_][ks_][(wid * 2 + 0) * 512]);             \
    g2l16(wet + bsrc[1] + ko, &Bs[db_][ks_][(wid * 2 + 1) * 512]);             \
    asm volatile("" ::: "memory"); }
#define RD_A(db_, ks_) {                                                       \
    _Pragma("unroll")                                                          \
    for (int fm = 0; fm < 8; ++fm) {                                           \
      const int row = wm * 128 + fm * 16 + (lane & 15);                        \
      af[fm] = __builtin_bit_cast(bf16x8, *(const uint4*)(                     \
          &As[db_][ks_][row * 32 + (((lane >> 4) ^ ((row >> 1) & 3)) * 8)]));} }
#define RD_B(db_, ks_, nh_) {                                                  \
    _Pragma("unroll")                                                          \
    for (int q = 0; q < 2; ++q) {                                              \
      const int fn = (nh_) * 2 + q;                                            \
      const int row = wn * 64 + fn * 16 + (lane & 15);                         \
      bfr[fn] = __builtin_bit_cast(bf16x8, *(const uint4*)(                    \
          &Bs[db_][ks_][row * 32 + (((lane >> 4) ^ ((row >> 1) & 3)) * 8)]));} }
#define VM8()  asm volatile("s_waitcnt vmcnt(8)" ::: "memory")
#define SBAR() { __builtin_amdgcn_sched_barrier(0);                            \
                 __builtin_amdgcn_s_barrier();                                 \
                 __builtin_amdgcn_sched_barrier(0); }
#define LGKM0() { asm volatile("s_waitcnt lgkmcnt(0)" ::: "memory");           \
                  __builtin_amdgcn_sched_barrier(0); }
#define MM(nh_) {                                                              \
    __builtin_amdgcn_s_setprio(1);                                             \
    _Pragma("unroll")                                                          \
    for (int fm = 0; fm < 8; ++fm) {                                           \
      acc[fm][(nh_) * 2] = __builtin_amdgcn_mfma_f32_16x16x32_bf16(            \
          af[fm], bfr[(nh_) * 2], acc[fm][(nh_) * 2], 0, 0, 0);                \
      acc[fm][(nh_) * 2 + 1] = __builtin_amdgcn_mfma_f32_16x16x32_bf16(        \
          af[fm], bfr[(nh_) * 2 + 1], acc[fm][(nh_) * 2 + 1], 0, 0, 0); }      \
    __builtin_amdgcn_s_setprio(0); }

  // ---- prologue: 6 half-stages (12 loads/thread) in FIFO slot order ----
  SG_A(0, 0, 0);  SG_B(0, 0, 0);     // kt0 k-half0
  SG_A(0, 1, 32); SG_B(0, 1, 32);    // kt0 k-half1
  SG_A(1, 0, 64); SG_B(1, 0, 64);    // kt1 k-half0
  VM8();                             // oldest 4 (kt0.k0) landed
  SBAR();

  // ---- main loop: 16 iterations x 2 K-tiles (kt0=2it in db0, kt1 in db1) ----
#pragma unroll 1
  for (int it = 0; it < 16; ++it) {
    const int kb = it * 128;   // short-col of kt0

    // p1: compute (db0,k0,nh0); stage db1.A.k1 (kt1)
    RD_A(0, 0); RD_B(0, 0, 0); SG_A(1, 1, kb + 96);
    SBAR(); LGKM0(); MM(0);
    // p2: compute (db0,k0,nh1); stage db1.B.k1
    RD_B(0, 0, 1); SG_B(1, 1, kb + 96); VM8();
    SBAR(); LGKM0(); MM(1);
    // p3: compute (db0,k1,nh0); stage db0.A.k0 (kt2)
    RD_A(0, 1); RD_B(0, 1, 0); SG_A(0, 0, kb + 128);
    SBAR(); LGKM0(); MM(0);
    // p4: compute (db0,k1,nh1); stage db0.B.k0
    RD_B(0, 1, 1); SG_B(0, 0, kb + 128); VM8();
    SBAR(); LGKM0(); MM(1);
    // p5: compute (db1,k0,nh0); stage db0.A.k1 (kt2)
    RD_A(1, 0); RD_B(1, 0, 0); SG_A(0, 1, kb + 160);
    SBAR(); LGKM0(); MM(0);
    // p6: compute (db1,k0,nh1); stage db0.B.k1
    RD_B(1, 0, 1); SG_B(0, 1, kb + 160); VM8();
    SBAR(); LGKM0(); MM(1);
    // p7: compute (db1,k1,nh0); stage db1.A.k0 (kt3)
    RD_A(1, 1); RD_B(1, 1, 0); SG_A(1, 0, kb + 192);
    SBAR(); LGKM0(); MM(0);
    // p8: compute (db1,k1,nh1); stage db1.B.k0
    RD_B(1, 1, 1); SG_B(1, 0, kb + 192); VM8();
    SBAR(); LGKM0(); MM(1);
  }

  // Epilogue: out[tok][h] += w * (acc + be[e][h]); C layout: col=lane&15,
  // row=(lane>>4)*4+reg
  float bias[4];
#pragma unroll
  for (int fn = 0; fn < 4; ++fn)
    bias[fn] = be[e * HIDDEN + h0 + wn * 64 + fn * 16 + (lane & 15)];

#pragma unroll
  for (int fm = 0; fm < 8; ++fm) {
    const int rbase = m0 + wm * 128 + fm * 16 + (lane >> 4) * 4;
#pragma unroll
    for (int reg = 0; reg < 4; ++reg) {
      const int r = rbase + reg;
      if (r < M) {
        const int tok = etok[r];
        const float w = ew[r];
        float* orow = out + (size_t)tok * HIDDEN + h0 + wn * 64 + (lane & 15);
#pragma unroll
        for (int fn = 0; fn < 4; ++fn)
          atomicAdd(orow + fn * 16, w * (acc[fm][fn][reg] + bias[fn]));
      }
    }
  }
#undef SG_A
#undef SG_B
#undef RD_A
#undef RD_B
#undef VM8
#undef SBAR
#undef LGKM0
#undef MM
}

// ---------------------------------------------------------------------------
extern "C" void kernel_launch(void* const* d_in, const int* in_sizes, int n_in,
                              void* d_out, int out_size, void* d_ws, size_t ws_size,
                              hipStream_t stream) {
  const float* x  = (const float*)d_in[0];
  const float* Wg = (const float*)d_in[1];
  const float* bg = (const float*)d_in[2];
  const float* We = (const float*)d_in[3];
  const float* be = (const float*)d_in[4];
  float* out = (float*)d_out;

  char* ws = (char*)d_ws;
  int*            cnt  = (int*)(ws + OFF_CNT);
  int*            btok = (int*)(ws + OFF_TOK);
  float*          bw   = (float*)(ws + OFF_W);
  unsigned short* xbf  = (unsigned short*)(ws + OFF_XBF);
  unsigned short* wet  = (unsigned short*)(ws + OFF_WET);

  hipMemsetAsync(d_out, 0, (size_t)out_size * sizeof(float), stream);
  hipMemsetAsync(cnt, 0, 8 * 32 * sizeof(int), stream);

  prep_kernel<<<GATE_BLOCKS + TPOSE_BLOCKS, 256, 0, stream>>>(
      x, Wg, bg, We, xbf, wet, cnt, btok, bw);
  moe_gemm<<<dim3(HIDDEN / 256, N_TOKENS / 256, N_EXP), 512, 0, stream>>>(
      xbf, wet, be, cnt, btok, bw, out);
}

// Round 5
// 515.631 us; speedup vs baseline: 1.1183x; 1.1042x over previous
//
#include <hip/hip_runtime.h>
#include <hip/hip_bf16.h>

// Problem constants
#define N_TOKENS 8192
#define D_IN     2048
#define HIDDEN   2048
#define N_EXP    8
#define CAP      N_TOKENS       // worst-case tokens per expert (top-2)
#define GATE_BLOCKS 256         // 32 tokens per block
#define TPOSE_BLOCKS (N_EXP * 32 * 32)  // 8192 (64x64 tiles)

typedef __bf16 bf16x8 __attribute__((ext_vector_type(8)));
typedef float  f32x4  __attribute__((ext_vector_type(4)));

// Workspace layout (bytes):
//   [0, 1024)              cnt[8*32]  (one counter per 128B line; zeroed per launch)
//   [4096, +8*CAP*4)       bucket_tok (token | slot<<13; slot0 = top1 expert)
//   [266240, +8*CAP*4)     bucket_w
//   [1<<20, +N*D*2)        x_bf16
//   [34603008, +E*D*H*2)   We_t  (bf16, [e][h][d])
//   [101711872, +N*H*4)    p1    (slot-1 partial outputs, f32) -- only if ws fits
#define OFF_CNT   0
#define OFF_TOK   4096
#define OFF_W     266240
#define OFF_XBF   1048576
#define OFF_WET   34603008
#define OFF_P1    101711872ull
#define WS_NEED   (OFF_P1 + (size_t)N_TOKENS * HIDDEN * 4)

__device__ __forceinline__ unsigned short f2bf(float f) {
  unsigned int u = __builtin_bit_cast(unsigned int, f);
  u += 0x7fffu + ((u >> 16) & 1u);   // RNE
  return (unsigned short)(u >> 16);
}

__device__ __forceinline__ void g2l16(const void* g, void* l) {
  // async global->LDS, 16B/lane; LDS dest is wave-uniform base + lane*16
  __builtin_amdgcn_global_load_lds(
      (__attribute__((address_space(1))) void*)g,
      (__attribute__((address_space(3))) void*)l, 16, 0, 0);
}

// ---------------------------------------------------------------------------
// Fused prep kernel:
//   blocks [0, GATE_BLOCKS)                : gating + x fp32->bf16 conversion
//   blocks [GATE_BLOCKS, +TPOSE_BLOCKS)    : We [e][d][h] f32 -> We_t [e][h][d] bf16
// ---------------------------------------------------------------------------
union PrepSM {
  float tile[64][68];      // transpose path (17.4 KB)
  struct {
    int   lcnt[8];
    int   base[8];
    int   ltok[8][32];     // per-block, per-expert token lists (<=32 tokens/block)
    float lw[8][32];
  } g;
};

__global__ __launch_bounds__(256) void prep_kernel(
    const float* __restrict__ x, const float* __restrict__ Wg,
    const float* __restrict__ bg, const float* __restrict__ We,
    unsigned short* __restrict__ xbf, unsigned short* __restrict__ wet,
    int* __restrict__ cnt, int* __restrict__ btok, float* __restrict__ bw)
{
  __shared__ PrepSM sm;
  const int tid = threadIdx.x;

  if (blockIdx.x >= GATE_BLOCKS) {
    // ---------------- transpose + bf16 convert ----------------
    const int id = blockIdx.x - GATE_BLOCKS;
    const int e  = id >> 10;
    const int rem = id & 1023;
    const int d0 = (rem >> 5) << 6;
    const int h0 = (rem & 31) << 6;
    const int r  = tid >> 2;     // 0..63
    const int g  = tid & 3;      // 0..3

    const float* src = We + ((size_t)e * D_IN + d0 + r) * HIDDEN + h0 + g * 16;
#pragma unroll
    for (int i = 0; i < 4; ++i)
      *(float4*)&sm.tile[r][g * 16 + i * 4] = *(const float4*)(src + i * 4);
    __syncthreads();

    union { unsigned short s[16]; uint4 q[2]; } u;
#pragma unroll
    for (int i = 0; i < 16; ++i) u.s[i] = f2bf(sm.tile[g * 16 + i][r]);
    uint4* dst = (uint4*)(wet + ((size_t)e * HIDDEN + h0 + r) * D_IN + d0 + g * 16);
    dst[0] = u.q[0];
    dst[1] = u.q[1];
    return;
  }

  // ---------------- gating (32 tokens/block, 8/wave) ----------------
  const int lane = tid & 63;
  const int wid  = tid >> 6;
  if (tid < 8) sm.g.lcnt[tid] = 0;
  __syncthreads();

  const int tb = blockIdx.x * 32 + wid * 8;
  for (int tk = 0; tk < 8; ++tk) {
    const int n = tb + tk;
    const float* xr = x + (size_t)n * D_IN;
    unsigned short* xbr = xbf + (size_t)n * D_IN;

    // fused x -> bf16 (vectorized, coalesced)
#pragma unroll
    for (int c = 0; c < 8; ++c) {
      const int d = c * 256 + lane * 4;
      float4 xv = *(const float4*)(xr + d);
      uint2 pk;
      pk.x = (unsigned int)f2bf(xv.x) | ((unsigned int)f2bf(xv.y) << 16);
      pk.y = (unsigned int)f2bf(xv.z) | ((unsigned int)f2bf(xv.w) << 16);
      *(uint2*)(xbr + d) = pk;
    }

    // logits: 1 d per lane -> Wg row load is 32B/lane at 32B stride
    float acc[8];
#pragma unroll
    for (int e = 0; e < 8; ++e) acc[e] = 0.f;
#pragma unroll 4
    for (int c = 0; c < 32; ++c) {
      const int d = c * 64 + lane;
      const float xv = xr[d];
      const float4 g0 = *(const float4*)(Wg + (size_t)d * 8);
      const float4 g1 = *(const float4*)(Wg + (size_t)d * 8 + 4);
      acc[0] += xv * g0.x; acc[1] += xv * g0.y;
      acc[2] += xv * g0.z; acc[3] += xv * g0.w;
      acc[4] += xv * g1.x; acc[5] += xv * g1.y;
      acc[6] += xv * g1.z; acc[7] += xv * g1.w;
    }
#pragma unroll
    for (int e = 0; e < 8; ++e) {
      float v = acc[e];
      v += __shfl_down(v, 32); v += __shfl_down(v, 16); v += __shfl_down(v, 8);
      v += __shfl_down(v, 4);  v += __shfl_down(v, 2);  v += __shfl_down(v, 1);
      acc[e] = v;
    }

    if (lane == 0) {
      float lg[8], p[8];
      float mx = -1e30f;
#pragma unroll
      for (int e = 0; e < 8; ++e) { lg[e] = acc[e] + bg[e]; mx = fmaxf(mx, lg[e]); }
      float s = 0.f;
#pragma unroll
      for (int e = 0; e < 8; ++e) { p[e] = expf(lg[e] - mx); s += p[e]; }
      const float inv = 1.f / s;
      int e1 = 0;
#pragma unroll
      for (int e = 1; e < 8; ++e) if (lg[e] > lg[e1]) e1 = e;
      int e2 = (e1 == 0) ? 1 : 0;
#pragma unroll
      for (int e = 0; e < 8; ++e) if (e != e1 && lg[e] > lg[e2]) e2 = e;

      // slot bit: 0 = this is the token's top-1 expert, 1 = top-2
      const int s1 = atomicAdd(&sm.g.lcnt[e1], 1);
      sm.g.ltok[e1][s1] = n;              sm.g.lw[e1][s1] = p[e1] * inv;
      const int s2 = atomicAdd(&sm.g.lcnt[e2], 1);
      sm.g.ltok[e2][s2] = n | (1 << 13);  sm.g.lw[e2][s2] = p[e2] * inv;
    }
  }
  __syncthreads();

  if (tid < 8) sm.g.base[tid] = atomicAdd(&cnt[tid * 32], sm.g.lcnt[tid]);
  __syncthreads();

  const int e = tid >> 5, i = tid & 31;
  if (i < sm.g.lcnt[e]) {
    const int o = e * CAP + sm.g.base[e] + i;
    btok[o] = sm.g.ltok[e][i];
    bw[o]   = sm.g.lw[e][i];
  }
}

// ---------------------------------------------------------------------------
// Grouped GEMM over expert buckets (128x128 tile, BK=64, bf16 MFMA)
// Proven round-0 2-phase core (654 TF-equiv) + two deltas:
//   1. T1 XCD swizzle: flat-id remap -> XCD k owns expert k; m-inner order
//      keeps the B h-panel (512 KB) L2-resident, A bucket (8 MB) L3-resident.
//   2. SLOTTED epilogue: plain stores to out (slot0) / p1 (slot1) instead of
//      33.5M f32 atomicAdds (L2-slice RMW serialization theory).
// LDS tiles XOR-swizzled (kc ^= row&7): bank conflicts = 0 (verified r0-r2).
// ---------------------------------------------------------------------------
template <int SLOTTED>
__global__ __launch_bounds__(256, 4) void moe_gemm(
    const unsigned short* __restrict__ xbf, const unsigned short* __restrict__ wet,
    const float* __restrict__ be, const int* __restrict__ cnt,
    const int* __restrict__ btok, const float* __restrict__ bw,
    float* __restrict__ out, float* __restrict__ p1)
{
  // XCD-aware swizzle: flat dispatch id -> (expert = XCD, h outer, m inner)
  const int flat = blockIdx.x + (blockIdx.y << 4) + (blockIdx.z << 10); // 0..8191
  const int swz  = ((flat & 7) << 10) + (flat >> 3);
  const int e    = swz >> 10;
  const int h0   = ((swz >> 6) & 15) << 7;
  const int m0   = (swz & 63) << 7;

  const int M = cnt[e * 32];
  if (m0 >= M) return;

  __shared__ __align__(16) unsigned short As[128 * 64];
  __shared__ __align__(16) unsigned short Bs[128 * 64];

  const int tid  = threadIdx.x;
  const int wid  = tid >> 6;
  const int lane = tid & 63;
  const int wm   = wid >> 1;   // 0..1
  const int wn   = wid & 1;    // 0..1

  const int* etok = btok + e * CAP;
  const float* ew = bw + e * CAP;

  // swizzled per-lane source column: data for k-chunk (c ^ localrow) goes at lane pos c
  const int kcs = (((lane & 7) ^ (lane >> 3)) * 8);

  size_t asrc[4], bsrc[4];
#pragma unroll
  for (int j = 0; j < 4; ++j) {
    const int c = wid * 4 + j;               // chunk 0..15 (8 rows each)
    const int r = c * 8 + (lane >> 3);       // row within 128-tile
    int ar = m0 + r;
    if (ar >= M) ar = m0;                    // clamp (discarded in epilogue)
    const int tok = etok[ar] & 8191;         // strip slot bit
    asrc[j] = (size_t)tok * D_IN + kcs;
    bsrc[j] = ((size_t)e * HIDDEN + h0 + r) * D_IN + kcs;
  }

  f32x4 acc[4][4];
#pragma unroll
  for (int i = 0; i < 4; ++i)
#pragma unroll
    for (int j = 0; j < 4; ++j) acc[i][j] = (f32x4){0.f, 0.f, 0.f, 0.f};

  for (int k0 = 0; k0 < D_IN; k0 += 64) {
    __syncthreads();  // previous tile fully consumed
#pragma unroll
    for (int j = 0; j < 4; ++j)
      g2l16(xbf + asrc[j] + k0, &As[(wid * 4 + j) * 512]);
#pragma unroll
    for (int j = 0; j < 4; ++j)
      g2l16(wet + bsrc[j] + k0, &Bs[(wid * 4 + j) * 512]);
    __syncthreads();  // tile staged

#pragma unroll
    for (int kh = 0; kh < 2; ++kh) {
      bf16x8 af[4], bfr[4];
#pragma unroll
      for (int fm = 0; fm < 4; ++fm) {
        const int row = wm * 64 + fm * 16 + (lane & 15);
        const int kc  = kh * 4 + (lane >> 4);
        af[fm] = __builtin_bit_cast(bf16x8,
            *(const uint4*)(As + row * 64 + ((kc ^ (row & 7)) * 8)));
      }
#pragma unroll
      for (int fn = 0; fn < 4; ++fn) {
        const int row = wn * 64 + fn * 16 + (lane & 15);
        const int kc  = kh * 4 + (lane >> 4);
        bfr[fn] = __builtin_bit_cast(bf16x8,
            *(const uint4*)(Bs + row * 64 + ((kc ^ (row & 7)) * 8)));
      }
#pragma unroll
      for (int fm = 0; fm < 4; ++fm)
#pragma unroll
        for (int fn = 0; fn < 4; ++fn)
          acc[fm][fn] = __builtin_amdgcn_mfma_f32_16x16x32_bf16(
              af[fm], bfr[fn], acc[fm][fn], 0, 0, 0);
    }
  }

  // Epilogue: val = w * (acc + be[e][h]); C layout: col=lane&15, row=(lane>>4)*4+reg
  float bias[4];
#pragma unroll
  for (int fn = 0; fn < 4; ++fn)
    bias[fn] = be[e * HIDDEN + h0 + wn * 64 + fn * 16 + (lane & 15)];

#pragma unroll
  for (int fm = 0; fm < 4; ++fm) {
    const int rbase = m0 + wm * 64 + fm * 16 + (lane >> 4) * 4;
#pragma unroll
    for (int reg = 0; reg < 4; ++reg) {
      const int r = rbase + reg;
      if (r < M) {
        const int tv  = etok[r];
        const int tok = tv & 8191;
        const float w = ew[r];
        if (SLOTTED) {
          // plain store: slot0 -> out, slot1 -> p1 (no RMW, no atomics)
          float* dst = ((tv >> 13) ? p1 : out) +
                       (size_t)tok * HIDDEN + h0 + wn * 64 + (lane & 15);
#pragma unroll
          for (int fn = 0; fn < 4; ++fn)
            dst[fn * 16] = w * (acc[fm][fn][reg] + bias[fn]);
        } else {
          float* orow = out + (size_t)tok * HIDDEN + h0 + wn * 64 + (lane & 15);
#pragma unroll
          for (int fn = 0; fn < 4; ++fn)
            atomicAdd(orow + fn * 16, w * (acc[fm][fn][reg] + bias[fn]));
        }
      }
    }
  }
}

// ---------------------------------------------------------------------------
// out += p1 (both fully written by the GEMM; no zero-init needed anywhere)
// ---------------------------------------------------------------------------
__global__ __launch_bounds__(256) void combine_kernel(
    float* __restrict__ out, const float* __restrict__ p1)
{
  const int stride = gridDim.x * 256;
  for (int i = blockIdx.x * 256 + threadIdx.x;
       i < N_TOKENS * HIDDEN / 4; i += stride) {
    float4 a = ((const float4*)out)[i];
    const float4 b = ((const float4*)p1)[i];
    a.x += b.x; a.y += b.y; a.z += b.z; a.w += b.w;
    ((float4*)out)[i] = a;
  }
}

// ---------------------------------------------------------------------------
extern "C" void kernel_launch(void* const* d_in, const int* in_sizes, int n_in,
                              void* d_out, int out_size, void* d_ws, size_t ws_size,
                              hipStream_t stream) {
  const float* x  = (const float*)d_in[0];
  const float* Wg = (const float*)d_in[1];
  const float* bg = (const float*)d_in[2];
  const float* We = (const float*)d_in[3];
  const float* be = (const float*)d_in[4];
  float* out = (float*)d_out;

  char* ws = (char*)d_ws;
  int*            cnt  = (int*)(ws + OFF_CNT);
  int*            btok = (int*)(ws + OFF_TOK);
  float*          bw   = (float*)(ws + OFF_W);
  unsigned short* xbf  = (unsigned short*)(ws + OFF_XBF);
  unsigned short* wet  = (unsigned short*)(ws + OFF_WET);
  float*          p1   = (float*)(ws + OFF_P1);

  const bool slotted = (ws_size >= WS_NEED);

  hipMemsetAsync(cnt, 0, 8 * 32 * sizeof(int), stream);
  if (!slotted)
    hipMemsetAsync(d_out, 0, (size_t)out_size * sizeof(float), stream);

  prep_kernel<<<GATE_BLOCKS + TPOSE_BLOCKS, 256, 0, stream>>>(
      x, Wg, bg, We, xbf, wet, cnt, btok, bw);

  if (slotted) {
    moe_gemm<1><<<dim3(HIDDEN / 128, N_TOKENS / 128, N_EXP), 256, 0, stream>>>(
        xbf, wet, be, cnt, btok, bw, out, p1);
    combine_kernel<<<2048, 256, 0, stream>>>(out, p1);
  } else {
    moe_gemm<0><<<dim3(HIDDEN / 128, N_TOKENS / 128, N_EXP), 256, 0, stream>>>(
        xbf, wet, be, cnt, btok, bw, out, p1);
  }
}

// Round 6
// 470.400 us; speedup vs baseline: 1.2258x; 1.0962x over previous
//
#include <hip/hip_runtime.h>
#include <hip/hip_bf16.h>

// Problem constants
#define N_TOKENS 8192
#define D_IN     2048
#define HIDDEN   2048
#define N_EXP    8
#define CAP      N_TOKENS       // worst-case tokens per expert (top-2)
#define GATE_BLOCKS 2048        // 4 tokens per block, 1 token per WAVE
#define TPOSE_BLOCKS (N_EXP * 32 * 32)  // 8192 (64x64 tiles)

typedef __bf16 bf16x8 __attribute__((ext_vector_type(8)));
typedef float  f32x4  __attribute__((ext_vector_type(4)));

// Workspace layout (bytes):
//   [0, 1024)              cnt[8*32]  (one counter per 128B line; zeroed per launch)
//   [4096, +8*CAP*4)       bucket_tok (token | slot<<13; slot0 = top1 expert)
//   [266240, +8*CAP*4)     bucket_w
//   [1<<20, +N*D*2)        x_bf16
//   [34603008, +E*D*H*2)   We_t  (bf16, [e][h][d])
//   [101711872, +N*H*4)    p1    (slot-1 partial outputs, f32) -- only if ws fits
#define OFF_CNT   0
#define OFF_TOK   4096
#define OFF_W     266240
#define OFF_XBF   1048576
#define OFF_WET   34603008
#define OFF_P1    101711872ull
#define WS_NEED   (OFF_P1 + (size_t)N_TOKENS * HIDDEN * 4)

__device__ __forceinline__ unsigned short f2bf(float f) {
  unsigned int u = __builtin_bit_cast(unsigned int, f);
  u += 0x7fffu + ((u >> 16) & 1u);   // RNE
  return (unsigned short)(u >> 16);
}

__device__ __forceinline__ void g2l16(const void* g, void* l) {
  // async global->LDS, 16B/lane; LDS dest is wave-uniform base + lane*16
  __builtin_amdgcn_global_load_lds(
      (__attribute__((address_space(1))) void*)g,
      (__attribute__((address_space(3))) void*)l, 16, 0, 0);
}

// ---------------------------------------------------------------------------
// Fused prep kernel:
//   blocks [0, GATE_BLOCKS)                : gating + x fp32->bf16 (1 token/wave)
//   blocks [GATE_BLOCKS, +TPOSE_BLOCKS)    : We [e][d][h] f32 -> We_t [e][h][d] bf16
// Round-6 delta: gating was 256 blocks x 8-token serial loop per wave
// (1 wave/SIMD latency-bound tail, est 100-150us). Now 2048 blocks, 1
// token/wave, 8192 waves -> latency hidden by TLP. Inner code unchanged.
// ---------------------------------------------------------------------------
union PrepSM {
  float tile[64][68];      // transpose path (17.4 KB)
  struct {
    int   lcnt[8];
    int   base[8];
    int   ltok[8][8];      // per-block lists (<=4 tokens x 2 slots per block)
    float lw[8][8];
  } g;
};

__global__ __launch_bounds__(256) void prep_kernel(
    const float* __restrict__ x, const float* __restrict__ Wg,
    const float* __restrict__ bg, const float* __restrict__ We,
    unsigned short* __restrict__ xbf, unsigned short* __restrict__ wet,
    int* __restrict__ cnt, int* __restrict__ btok, float* __restrict__ bw)
{
  __shared__ PrepSM sm;
  const int tid = threadIdx.x;

  if (blockIdx.x >= GATE_BLOCKS) {
    // ---------------- transpose + bf16 convert ----------------
    const int id = blockIdx.x - GATE_BLOCKS;
    const int e  = id >> 10;
    const int rem = id & 1023;
    const int d0 = (rem >> 5) << 6;
    const int h0 = (rem & 31) << 6;
    const int r  = tid >> 2;     // 0..63
    const int g  = tid & 3;      // 0..3

    const float* src = We + ((size_t)e * D_IN + d0 + r) * HIDDEN + h0 + g * 16;
#pragma unroll
    for (int i = 0; i < 4; ++i)
      *(float4*)&sm.tile[r][g * 16 + i * 4] = *(const float4*)(src + i * 4);
    __syncthreads();

    union { unsigned short s[16]; uint4 q[2]; } u;
#pragma unroll
    for (int i = 0; i < 16; ++i) u.s[i] = f2bf(sm.tile[g * 16 + i][r]);
    uint4* dst = (uint4*)(wet + ((size_t)e * HIDDEN + h0 + r) * D_IN + d0 + g * 16);
    dst[0] = u.q[0];
    dst[1] = u.q[1];
    return;
  }

  // ---------------- gating (4 tokens/block, 1 token/WAVE) ----------------
  const int lane = tid & 63;
  const int wid  = tid >> 6;
  if (tid < 8) sm.g.lcnt[tid] = 0;
  __syncthreads();

  {
    const int n = blockIdx.x * 4 + wid;
    const float* xr = x + (size_t)n * D_IN;
    unsigned short* xbr = xbf + (size_t)n * D_IN;

    // fused x -> bf16 (vectorized, coalesced)
#pragma unroll
    for (int c = 0; c < 8; ++c) {
      const int d = c * 256 + lane * 4;
      float4 xv = *(const float4*)(xr + d);
      uint2 pk;
      pk.x = (unsigned int)f2bf(xv.x) | ((unsigned int)f2bf(xv.y) << 16);
      pk.y = (unsigned int)f2bf(xv.z) | ((unsigned int)f2bf(xv.w) << 16);
      *(uint2*)(xbr + d) = pk;
    }

    // logits: 1 d per lane -> Wg row load is 32B/lane (L1-resident after warmup)
    float acc[8];
#pragma unroll
    for (int e = 0; e < 8; ++e) acc[e] = 0.f;
#pragma unroll 4
    for (int c = 0; c < 32; ++c) {
      const int d = c * 64 + lane;
      const float xv = xr[d];
      const float4 g0 = *(const float4*)(Wg + (size_t)d * 8);
      const float4 g1 = *(const float4*)(Wg + (size_t)d * 8 + 4);
      acc[0] += xv * g0.x; acc[1] += xv * g0.y;
      acc[2] += xv * g0.z; acc[3] += xv * g0.w;
      acc[4] += xv * g1.x; acc[5] += xv * g1.y;
      acc[6] += xv * g1.z; acc[7] += xv * g1.w;
    }
#pragma unroll
    for (int e = 0; e < 8; ++e) {
      float v = acc[e];
      v += __shfl_down(v, 32); v += __shfl_down(v, 16); v += __shfl_down(v, 8);
      v += __shfl_down(v, 4);  v += __shfl_down(v, 2);  v += __shfl_down(v, 1);
      acc[e] = v;
    }

    if (lane == 0) {
      float lg[8], p[8];
      float mx = -1e30f;
#pragma unroll
      for (int e = 0; e < 8; ++e) { lg[e] = acc[e] + bg[e]; mx = fmaxf(mx, lg[e]); }
      float s = 0.f;
#pragma unroll
      for (int e = 0; e < 8; ++e) { p[e] = expf(lg[e] - mx); s += p[e]; }
      const float inv = 1.f / s;
      int e1 = 0;
#pragma unroll
      for (int e = 1; e < 8; ++e) if (lg[e] > lg[e1]) e1 = e;
      int e2 = (e1 == 0) ? 1 : 0;
#pragma unroll
      for (int e = 0; e < 8; ++e) if (e != e1 && lg[e] > lg[e2]) e2 = e;

      // slot bit: 0 = this is the token's top-1 expert, 1 = top-2
      const int s1 = atomicAdd(&sm.g.lcnt[e1], 1);
      sm.g.ltok[e1][s1] = n;              sm.g.lw[e1][s1] = p[e1] * inv;
      const int s2 = atomicAdd(&sm.g.lcnt[e2], 1);
      sm.g.ltok[e2][s2] = n | (1 << 13);  sm.g.lw[e2][s2] = p[e2] * inv;
    }
  }
  __syncthreads();

  // one global atomic per expert per block (counters on separate 128B lines)
  if (tid < 8) sm.g.base[tid] = atomicAdd(&cnt[tid * 32], sm.g.lcnt[tid]);
  __syncthreads();

  const int e = tid >> 5, i = tid & 31;
  if (i < sm.g.lcnt[e]) {
    const int o = e * CAP + sm.g.base[e] + i;
    btok[o] = sm.g.ltok[e][i];
    bw[o]   = sm.g.lw[e][i];
  }
}

// ---------------------------------------------------------------------------
// Grouped GEMM over expert buckets (128x128 tile, BK=64, bf16 MFMA)
// Round-5 verified core (172us, MfmaUtil 35%): 2-phase 128^2 + T1 XCD
// swizzle + SLOTTED epilogue (plain stores, no atomics). UNCHANGED this round.
// ---------------------------------------------------------------------------
template <int SLOTTED>
__global__ __launch_bounds__(256, 4) void moe_gemm(
    const unsigned short* __restrict__ xbf, const unsigned short* __restrict__ wet,
    const float* __restrict__ be, const int* __restrict__ cnt,
    const int* __restrict__ btok, const float* __restrict__ bw,
    float* __restrict__ out, float* __restrict__ p1)
{
  // XCD-aware swizzle: flat dispatch id -> (expert = XCD, h outer, m inner)
  const int flat = blockIdx.x + (blockIdx.y << 4) + (blockIdx.z << 10); // 0..8191
  const int swz  = ((flat & 7) << 10) + (flat >> 3);
  const int e    = swz >> 10;
  const int h0   = ((swz >> 6) & 15) << 7;
  const int m0   = (swz & 63) << 7;

  const int M = cnt[e * 32];
  if (m0 >= M) return;

  __shared__ __align__(16) unsigned short As[128 * 64];
  __shared__ __align__(16) unsigned short Bs[128 * 64];

  const int tid  = threadIdx.x;
  const int wid  = tid >> 6;
  const int lane = tid & 63;
  const int wm   = wid >> 1;   // 0..1
  const int wn   = wid & 1;    // 0..1

  const int* etok = btok + e * CAP;
  const float* ew = bw + e * CAP;

  // swizzled per-lane source column: data for k-chunk (c ^ localrow) goes at lane pos c
  const int kcs = (((lane & 7) ^ (lane >> 3)) * 8);

  size_t asrc[4], bsrc[4];
#pragma unroll
  for (int j = 0; j < 4; ++j) {
    const int c = wid * 4 + j;               // chunk 0..15 (8 rows each)
    const int r = c * 8 + (lane >> 3);       // row within 128-tile
    int ar = m0 + r;
    if (ar >= M) ar = m0;                    // clamp (discarded in epilogue)
    const int tok = etok[ar] & 8191;         // strip slot bit
    asrc[j] = (size_t)tok * D_IN + kcs;
    bsrc[j] = ((size_t)e * HIDDEN + h0 + r) * D_IN + kcs;
  }

  f32x4 acc[4][4];
#pragma unroll
  for (int i = 0; i < 4; ++i)
#pragma unroll
    for (int j = 0; j < 4; ++j) acc[i][j] = (f32x4){0.f, 0.f, 0.f, 0.f};

  for (int k0 = 0; k0 < D_IN; k0 += 64) {
    __syncthreads();  // previous tile fully consumed
#pragma unroll
    for (int j = 0; j < 4; ++j)
      g2l16(xbf + asrc[j] + k0, &As[(wid * 4 + j) * 512]);
#pragma unroll
    for (int j = 0; j < 4; ++j)
      g2l16(wet + bsrc[j] + k0, &Bs[(wid * 4 + j) * 512]);
    __syncthreads();  // tile staged

#pragma unroll
    for (int kh = 0; kh < 2; ++kh) {
      bf16x8 af[4], bfr[4];
#pragma unroll
      for (int fm = 0; fm < 4; ++fm) {
        const int row = wm * 64 + fm * 16 + (lane & 15);
        const int kc  = kh * 4 + (lane >> 4);
        af[fm] = __builtin_bit_cast(bf16x8,
            *(const uint4*)(As + row * 64 + ((kc ^ (row & 7)) * 8)));
      }
#pragma unroll
      for (int fn = 0; fn < 4; ++fn) {
        const int row = wn * 64 + fn * 16 + (lane & 15);
        const int kc  = kh * 4 + (lane >> 4);
        bfr[fn] = __builtin_bit_cast(bf16x8,
            *(const uint4*)(Bs + row * 64 + ((kc ^ (row & 7)) * 8)));
      }
#pragma unroll
      for (int fm = 0; fm < 4; ++fm)
#pragma unroll
        for (int fn = 0; fn < 4; ++fn)
          acc[fm][fn] = __builtin_amdgcn_mfma_f32_16x16x32_bf16(
              af[fm], bfr[fn], acc[fm][fn], 0, 0, 0);
    }
  }

  // Epilogue: val = w * (acc + be[e][h]); C layout: col=lane&15, row=(lane>>4)*4+reg
  float bias[4];
#pragma unroll
  for (int fn = 0; fn < 4; ++fn)
    bias[fn] = be[e * HIDDEN + h0 + wn * 64 + fn * 16 + (lane & 15)];

#pragma unroll
  for (int fm = 0; fm < 4; ++fm) {
    const int rbase = m0 + wm * 64 + fm * 16 + (lane >> 4) * 4;
#pragma unroll
    for (int reg = 0; reg < 4; ++reg) {
      const int r = rbase + reg;
      if (r < M) {
        const int tv  = etok[r];
        const int tok = tv & 8191;
        const float w = ew[r];
        if (SLOTTED) {
          // plain store: slot0 -> out, slot1 -> p1 (no RMW, no atomics)
          float* dst = ((tv >> 13) ? p1 : out) +
                       (size_t)tok * HIDDEN + h0 + wn * 64 + (lane & 15);
#pragma unroll
          for (int fn = 0; fn < 4; ++fn)
            dst[fn * 16] = w * (acc[fm][fn][reg] + bias[fn]);
        } else {
          float* orow = out + (size_t)tok * HIDDEN + h0 + wn * 64 + (lane & 15);
#pragma unroll
          for (int fn = 0; fn < 4; ++fn)
            atomicAdd(orow + fn * 16, w * (acc[fm][fn][reg] + bias[fn]));
        }
      }
    }
  }
}

// ---------------------------------------------------------------------------
// out += p1 (both fully written by the GEMM; no zero-init needed anywhere)
// ---------------------------------------------------------------------------
__global__ __launch_bounds__(256) void combine_kernel(
    float* __restrict__ out, const float* __restrict__ p1)
{
  const int stride = gridDim.x * 256;
  for (int i = blockIdx.x * 256 + threadIdx.x;
       i < N_TOKENS * HIDDEN / 4; i += stride) {
    float4 a = ((const float4*)out)[i];
    const float4 b = ((const float4*)p1)[i];
    a.x += b.x; a.y += b.y; a.z += b.z; a.w += b.w;
    ((float4*)out)[i] = a;
  }
}

// ---------------------------------------------------------------------------
extern "C" void kernel_launch(void* const* d_in, const int* in_sizes, int n_in,
                              void* d_out, int out_size, void* d_ws, size_t ws_size,
                              hipStream_t stream) {
  const float* x  = (const float*)d_in[0];
  const float* Wg = (const float*)d_in[1];
  const float* bg = (const float*)d_in[2];
  const float* We = (const float*)d_in[3];
  const float* be = (const float*)d_in[4];
  float* out = (float*)d_out;

  char* ws = (char*)d_ws;
  int*            cnt  = (int*)(ws + OFF_CNT);
  int*            btok = (int*)(ws + OFF_TOK);
  float*          bw   = (float*)(ws + OFF_W);
  unsigned short* xbf  = (unsigned short*)(ws + OFF_XBF);
  unsigned short* wet  = (unsigned short*)(ws + OFF_WET);
  float*          p1   = (float*)(ws + OFF_P1);

  const bool slotted = (ws_size >= WS_NEED);

  hipMemsetAsync(cnt, 0, 8 * 32 * sizeof(int), stream);
  if (!slotted)
    hipMemsetAsync(d_out, 0, (size_t)out_size * sizeof(float), stream);

  prep_kernel<<<GATE_BLOCKS + TPOSE_BLOCKS, 256, 0, stream>>>(
      x, Wg, bg, We, xbf, wet, cnt, btok, bw);

  if (slotted) {
    moe_gemm<1><<<dim3(HIDDEN / 128, N_TOKENS / 128, N_EXP), 256, 0, stream>>>(
        xbf, wet, be, cnt, btok, bw, out, p1);
    combine_kernel<<<2048, 256, 0, stream>>>(out, p1);
  } else {
    moe_gemm<0><<<dim3(HIDDEN / 128, N_TOKENS / 128, N_EXP), 256, 0, stream>>>(
        xbf, wet, be, cnt, btok, bw, out, p1);
  }
}